// Round 7
// baseline (3932.986 us; speedup 1.0000x reference)
//
#include <hip/hip_runtime.h>
#include <hip/hip_fp16.h>

#define N_NODES 50000
#define N_EDGES 400000
#define NCLS 4
#define HID 32
#define HI 36                        // HID + IN_DIM
#define ROWS_P (N_NODES * NCLS)      // 200000 per-plane (n,c) rows

// tanh(x) = 1 - 2/(exp(2x)+1); clamp avoids inf*0 NaN in the NR step.
__device__ __forceinline__ float fast_tanh(float x) {
    x = fminf(15.0f, fmaxf(-15.0f, x));
    float e = __expf(2.0f * x);
    float d = 1.0f + e;
    float r = __builtin_amdgcn_rcpf(d);
    r = r * (2.0f - d * r);   // one Newton step
    return 1.0f - 2.0f * r;
}

union F4H8 { float4 f4; __half2 h2[4]; };

// Per plane: m[n][c][0:32] = tanh(x @ inW + inb), m[n][c][32:36] = x (same across c)
__global__ void k_init(const float* __restrict__ x, const float* __restrict__ W,
                       const float* __restrict__ b, float* __restrict__ m) {
    unsigned t = blockIdx.x * 256 + threadIdx.x;
    if (t >= N_NODES * HI) return;
    unsigned idx = t % HI;
    unsigned n   = t / HI;
    float x0 = x[n * 4 + 0], x1 = x[n * 4 + 1];
    float x2 = x[n * 4 + 2], x3 = x[n * 4 + 3];
    float val;
    if (idx < 32) {
        float a = b[idx];
        a += x0 * W[idx] + x1 * W[32 + idx] + x2 * W[64 + idx] + x3 * W[96 + idx];
        val = fast_tanh(a);
    } else {
        val = (idx == 32) ? x0 : (idx == 33) ? x1 : (idx == 34) ? x2 : x3;
    }
    float* dst = m + (size_t)n * (NCLS * HI) + idx;
    dst[0] = val; dst[HI] = val; dst[2 * HI] = val; dst[3 * HI] = val;
}

// ---------------- CSR build (per plane, once) ----------------
__global__ void k_hist(const int* __restrict__ rowI, const int* __restrict__ colI,
                       int* __restrict__ inCnt, int* __restrict__ outCnt) {
    unsigned e = blockIdx.x * 256 + threadIdx.x;
    if (e >= N_EDGES) return;
    atomicAdd(&inCnt[colI[e]], 1);
    atomicAdd(&outCnt[rowI[e]], 1);
}

// Exclusive scan of 50000 counts -> 50001 offsets. block 0: in, block 1: out.
__global__ void k_scan(const int* __restrict__ inCnt, const int* __restrict__ outCnt,
                       int* __restrict__ inOff, int* __restrict__ outOff) {
    const int* cnt = blockIdx.x ? outCnt : inCnt;
    int*       off = blockIdx.x ? outOff : inOff;
    __shared__ int sh[16];
    __shared__ int carry;
    int tid = threadIdx.x;            // 1024
    int lane = tid & 63, wid = tid >> 6;
    if (tid == 0) carry = 0;
    __syncthreads();
    for (int base = 0; base < N_NODES; base += 1024) {
        int i = base + tid;
        int v = (i < N_NODES) ? cnt[i] : 0;
        int val = v;
#pragma unroll
        for (int d = 1; d < 64; d <<= 1) {
            int t = __shfl_up(val, d, 64);
            if (lane >= d) val += t;
        }
        if (lane == 63) sh[wid] = val;
        __syncthreads();
        if (tid < 16) {
            int s = sh[tid];
#pragma unroll
            for (int d = 1; d < 16; d <<= 1) {
                int t = __shfl_up(s, d, 16);
                if (tid >= d) s += t;
            }
            sh[tid] = s;
        }
        __syncthreads();
        int waveOff = (wid == 0) ? 0 : sh[wid - 1];
        int incl = val + waveOff + carry;
        if (i < N_NODES) off[i] = incl - v;
        __syncthreads();
        if (tid == 1023) carry = incl;
        __syncthreads();
    }
    if (tid == 0) off[N_NODES] = carry;
}

// inL[pi]=(e,row,col,posOut) for k_edge (in-CSR order).
// mergedL[node n's slots] = (code, aIdx): in-entries (code=row, aIdx=pi) then
// out-entries (code=N_NODES+col, aIdx=E+po). Node n's merged range:
// [inOff[n]+outOff[n], inOff[n+1]+outOff[n+1]).
__global__ void k_fill(const int* __restrict__ rowI, const int* __restrict__ colI,
                       const int* __restrict__ inOff, const int* __restrict__ outOff,
                       int* __restrict__ inCur, int* __restrict__ outCur,
                       int4* __restrict__ inL, int2* __restrict__ mergedL) {
    unsigned e = blockIdx.x * 256 + threadIdx.x;
    if (e >= N_EDGES) return;
    int r = rowI[e], cn = colI[e];
    int liIn = atomicAdd(&inCur[cn], 1);
    int pi = inOff[cn] + liIn;
    int liOut = atomicAdd(&outCur[r], 1);
    int po = outOff[r] + liOut;
    inL[pi] = make_int4((int)e, r, cn, po);
    mergedL[inOff[cn] + outOff[cn] + liIn] = make_int2(r, pi);
    int degInR = inOff[r + 1] - inOff[r];
    mergedL[inOff[r] + outOff[r] + degInR + liOut] =
        make_int2(N_NODES + cn, N_EDGES + po);
}

// ---------------- per-iteration kernels ----------------

// Fused projection: 128 fp16 cols (u|v from eW1, p|q from nW1[0:72]), 2 rows/thread.
// outBase planes are contiguous: u, v, p, q each ROWS_P*32 halves.
__global__ void k_gemm_fused(const float* __restrict__ m, const float* __restrict__ eW1,
                             const float* __restrict__ nW1, __half* __restrict__ outBase) {
    unsigned g  = blockIdx.x * 256 + threadIdx.x;   // exact grid: (ROWS_P/2)*128
    unsigned pr = g >> 7;
    unsigned o  = g & 127;
    unsigned r0 = pr * 2;
    const float4* m40 = reinterpret_cast<const float4*>(m + (size_t)r0 * HI);
    const float4* m41 = reinterpret_cast<const float4*>(m + (size_t)(r0 + 1) * HI);
    float mr0[36], mr1[36];
#pragma unroll
    for (int i = 0; i < 9; ++i) {
        float4 a = m40[i], b = m41[i];
        mr0[4 * i] = a.x; mr0[4 * i + 1] = a.y; mr0[4 * i + 2] = a.z; mr0[4 * i + 3] = a.w;
        mr1[4 * i] = b.x; mr1[4 * i + 1] = b.y; mr1[4 * i + 2] = b.z; mr1[4 * i + 3] = b.w;
    }
    unsigned sub = o >> 5, oo = o & 31;
    const float* wc = (sub < 2 ? eW1 + sub * (36 * 32)
                               : nW1 + (sub - 2) * (36 * 32)) + oo;
    float a0 = 0.f, a1 = 0.f;
#pragma unroll
    for (int k = 0; k < 36; ++k) {
        float w = wc[k * 32];
        a0 += mr0[k] * w;
        a1 += mr1[k] * w;
    }
    __half* dst = outBase + (size_t)sub * ((size_t)ROWS_P * 32);
    dst[(size_t)r0 * 32 + oo]       = __float2half_rn(a0);
    dst[(size_t)(r0 + 1) * 32 + oo] = __float2half_rn(a1);
}

// Final-pass projection: u|v only.
__global__ void k_gemm_uv(const float* __restrict__ m, const float* __restrict__ W,
                          __half* __restrict__ out0, __half* __restrict__ out1) {
    unsigned g  = blockIdx.x * 256 + threadIdx.x;   // exact grid: (ROWS_P/2)*64
    unsigned pr = g >> 6;
    unsigned o  = g & 63;
    unsigned r0 = pr * 2;
    const float4* m40 = reinterpret_cast<const float4*>(m + (size_t)r0 * HI);
    const float4* m41 = reinterpret_cast<const float4*>(m + (size_t)(r0 + 1) * HI);
    float mr0[36], mr1[36];
#pragma unroll
    for (int i = 0; i < 9; ++i) {
        float4 a = m40[i], b = m41[i];
        mr0[4 * i] = a.x; mr0[4 * i + 1] = a.y; mr0[4 * i + 2] = a.z; mr0[4 * i + 3] = a.w;
        mr1[4 * i] = b.x; mr1[4 * i + 1] = b.y; mr1[4 * i + 2] = b.z; mr1[4 * i + 3] = b.w;
    }
    unsigned sub = o >> 5, oo = o & 31;
    const float* wc = W + (sub * 36) * 32 + oo;
    float a0 = 0.f, a1 = 0.f;
#pragma unroll
    for (int k = 0; k < 36; ++k) {
        float w = wc[k * 32];
        a0 += mr0[k] * w;
        a1 += mr1[k] * w;
    }
    __half* dst = sub ? out1 : out0;
    dst[(size_t)r0 * 32 + oo]       = __float2half_rn(a0);
    dst[(size_t)(r0 + 1) * 32 + oo] = __float2half_rn(a1);
}

// Edges in in-CSR order (grouped by col -> u side L1-resident).
// Per (idx,c): s = tanh(sum_o tanh(u[col]+v[row]+b1)*w2 + b2); softmax over c (4 lanes).
template <bool FINAL>
__global__ void k_edge(const int4* __restrict__ inL, const __half* __restrict__ u,
                       const __half* __restrict__ v, const float* __restrict__ b1,
                       const float* __restrict__ w2, const float* __restrict__ b2,
                       float* __restrict__ eaIn, float* __restrict__ eaOut,
                       float* __restrict__ dst) {
    unsigned g   = blockIdx.x * 256 + threadIdx.x;   // exact grid: E*4
    unsigned c   = g & 3;
    unsigned idx = g >> 2;
    int4 ent = inL[idx];   // (e, row, col, posOut)
    const float4* u4 = reinterpret_cast<const float4*>(u + ((unsigned)ent.z * 4 + c) * 32);
    const float4* v4 = reinterpret_cast<const float4*>(v + ((unsigned)ent.y * 4 + c) * 32);
    float t2 = b2[0];
#pragma unroll
    for (int i = 0; i < 4; ++i) {          // 4 x (16B = 8 halves)
        F4H8 U, V; U.f4 = u4[i]; V.f4 = v4[i];
#pragma unroll
        for (int jj = 0; jj < 4; ++jj) {
            float2 uf = __half22float2(U.h2[jj]);
            float2 vf = __half22float2(V.h2[jj]);
            int o = i * 8 + jj * 2;
            t2 += fast_tanh(uf.x + vf.x + b1[o])     * w2[o];
            t2 += fast_tanh(uf.y + vf.y + b1[o + 1]) * w2[o + 1];
        }
    }
    float s  = fast_tanh(t2);
    float m1 = fmaxf(s, __shfl_xor(s, 1, 4));
    float mx = fmaxf(m1, __shfl_xor(m1, 2, 4));
    float ex = __expf(s - mx);
    float sm = ex + __shfl_xor(ex, 1, 4);
    sm = sm + __shfl_xor(sm, 2, 4);
    float val = ex / sm;
    if (FINAL) {
        dst[(unsigned)ent.x * 4 + c] = val;
    } else {
        eaIn[g] = val;
        eaOut[(unsigned)ent.w * 4 + c] = val;
    }
}

// Fused node net, single merged gather list (in+out), unsigned addressing.
// h = m@C + nb1 + sum_merged a * pq[code*128 + c*32 + k];
// H = tanh(tanh(h) @ nW2 + nb2) -> m[row][0:32] in place. 8 rows x 32 lanes.
__global__ void k_node(float* __restrict__ m, const __half* __restrict__ pq,
                       const float* __restrict__ eaAll,
                       const int* __restrict__ inOff, const int* __restrict__ outOff,
                       const int2* __restrict__ mergedL,
                       const float* __restrict__ WC, const float* __restrict__ nb1,
                       const float* __restrict__ nW2, const float* __restrict__ nb2) {
    __shared__ float sC[36 * 32];
    __shared__ float sW2[32 * 32];
    __shared__ float tb[8 * 33];
    unsigned tid = threadIdx.x;
    for (unsigned i = tid; i < 36 * 32; i += 256) sC[i] = WC[i];
    for (unsigned i = tid; i < 32 * 32; i += 256) sW2[i] = nW2[i];
    unsigned rl = tid >> 5, k = tid & 31;
    unsigned row = blockIdx.x * 8 + rl;   // flat (n*4 + c)
    unsigned n = row >> 2, c = row & 3;
    const float4* m4 = reinterpret_cast<const float4*>(m + (size_t)row * HI);
    float mr[36];
#pragma unroll
    for (int i = 0; i < 9; ++i) {
        float4 v = m4[i];
        mr[4 * i] = v.x; mr[4 * i + 1] = v.y; mr[4 * i + 2] = v.z; mr[4 * i + 3] = v.w;
    }
    __syncthreads();
    float h = nb1[k];
#pragma unroll
    for (int kk = 0; kk < 36; ++kk) h += mr[kk] * sC[kk * 32 + k];

    // merged gather: batch-16 independent loads; dummy slots alias slot m0 w/ a=0.
    int m0 = inOff[n] + outOff[n];
    int m1 = inOff[n + 1] + outOff[n + 1];
    unsigned gOff = c * 32 + k;
    for (int base = m0; base < m1; base += 16) {
        unsigned adr[16]; float av[16];
#pragma unroll
        for (int kk = 0; kk < 16; ++kk) {
            int off = base + kk;
            bool ok = off < m1;
            int sa = ok ? off : m0;
            int2 L = mergedL[sa];
            adr[kk] = (unsigned)L.x * 128u + gOff;
            av[kk]  = ok ? eaAll[(unsigned)L.y * 4u + c] : 0.f;
        }
#pragma unroll
        for (int kk = 0; kk < 16; ++kk)
            h += av[kk] * __half2float(pq[adr[kk]]);
    }
    float t = fast_tanh(h);
    tb[rl * 33 + k] = t;
    __syncthreads();
    float hh = nb2[k];
#pragma unroll
    for (int kk = 0; kk < 32; ++kk) hh += tb[rl * 33 + kk] * sW2[kk * 32 + k];
    m[(size_t)row * HI + k] = fast_tanh(hh);
}

extern "C" void kernel_launch(void* const* d_in, const int* in_sizes, int n_in,
                              void* d_out, int out_size, void* d_ws, size_t ws_size,
                              hipStream_t stream) {
    const float* x   = (const float*)d_in[0];
    const int*   ei  = (const int*)d_in[1];
    const float* inW = (const float*)d_in[2];
    const float* inb = (const float*)d_in[3];
    const float* eW1 = (const float*)d_in[4];
    const float* eb1 = (const float*)d_in[5];
    const float* eW2 = (const float*)d_in[6];
    const float* eb2 = (const float*)d_in[7];
    const float* nW1 = (const float*)d_in[8];
    const float* nb1 = (const float*)d_in[9];
    const float* nW2 = (const float*)d_in[10];
    const float* nb2 = (const float*)d_in[11];
    float* out = (float*)d_out;

    // Workspace: m 28.8 | u,v,p,q fp16 51.2 | eaAll 12.8 | inL 6.4 | mergedL 6.4 |
    // offsets/counts ~0.8  => ~106 MB
    float*  m     = (float*)d_ws;
    __half* u     = (__half*)(m + (size_t)ROWS_P * HI);
    __half* v     = u + (size_t)ROWS_P * 32;
    __half* p     = v + (size_t)ROWS_P * 32;          // pq base (q = p + ROWS_P*32)
    float*  eaAll = (float*)(p + (size_t)2 * ROWS_P * 32);
    int4*   inL   = (int4*)(eaAll + (size_t)8 * N_EDGES);
    int2*   mrg   = (int2*)(inL + N_EDGES);
    int*    inOff  = (int*)(mrg + (size_t)2 * N_EDGES);
    int*    outOff = inOff + (N_NODES + 1);
    int*    inCnt  = outOff + (N_NODES + 1);
    int*    outCnt = inCnt + N_NODES;

    float* eaIn  = eaAll;
    float* eaOut = eaAll + (size_t)4 * N_EDGES;

    const int gridE = (N_EDGES + 255) / 256;

    for (int j = 0; j < 3; ++j) {
        const int*   rowI = ei + (size_t)j * 2 * N_EDGES;
        const int*   colI = rowI + N_EDGES;
        const float* eW1j = eW1 + j * 72 * 32;
        const float* eb1j = eb1 + j * 32;
        const float* eW2j = eW2 + j * 32;
        const float* eb2j = eb2 + j;
        const float* nW1j = nW1 + j * 108 * 32;
        const float* nb1j = nb1 + j * 32;
        const float* nW2j = nW2 + j * 1024;
        const float* nb2j = nb2 + j * 32;

        // CSR build
        hipMemsetAsync(inCnt, 0, 2 * N_NODES * sizeof(int), stream);
        k_hist<<<gridE, 256, 0, stream>>>(rowI, colI, inCnt, outCnt);
        k_scan<<<2, 1024, 0, stream>>>(inCnt, outCnt, inOff, outOff);
        hipMemsetAsync(inCnt, 0, 2 * N_NODES * sizeof(int), stream);
        k_fill<<<gridE, 256, 0, stream>>>(rowI, colI, inOff, outOff, inCnt, outCnt,
                                          inL, mrg);

        k_init<<<(N_NODES * HI + 255) / 256, 256, 0, stream>>>(
            x + (size_t)j * N_NODES * 4, inW + j * 128, inb + j * 32, m);

        for (int it = 0; it < 3; ++it) {
            k_gemm_fused<<<(ROWS_P / 2) * 128 / 256, 256, 0, stream>>>(m, eW1j, nW1j, u);
            k_edge<false><<<N_EDGES * 4 / 256, 256, 0, stream>>>(
                inL, u, v, eb1j, eW2j, eb2j, eaIn, eaOut, nullptr);
            k_node<<<ROWS_P / 8, 256, 0, stream>>>(m, p, eaAll, inOff, outOff, mrg,
                                                   nW1j + 72 * 32, nb1j, nW2j, nb2j);
        }
        k_gemm_uv<<<(ROWS_P / 2) * 64 / 256, 256, 0, stream>>>(m, eW1j, u, v);
        k_edge<true><<<N_EDGES * 4 / 256, 256, 0, stream>>>(
            inL, u, v, eb1j, eW2j, eb2j, nullptr, nullptr, out + (size_t)j * N_EDGES * 4);
    }
}

// Round 8
// 2998.866 us; speedup vs baseline: 1.3115x; 1.3115x over previous
//
#include <hip/hip_runtime.h>
#include <hip/hip_fp16.h>

#define N_NODES 50000
#define N_EDGES 400000
#define NCLS 4
#define HID 32
#define HI 36                        // HID + IN_DIM
#define ROWS_P (N_NODES * NCLS)      // 200000 per-plane (n,c) rows
#define PADCAP 672000                // padded list capacity (E + ~3.5*N expected, 32-sigma safe)

// tanh(x) = 1 - 2/(exp(2x)+1); clamp avoids inf*0 NaN in the NR step.
__device__ __forceinline__ float fast_tanh(float x) {
    x = fminf(15.0f, fmaxf(-15.0f, x));
    float e = __expf(2.0f * x);
    float d = 1.0f + e;
    float r = __builtin_amdgcn_rcpf(d);
    r = r * (2.0f - d * r);   // one Newton step
    return 1.0f - 2.0f * r;
}

union F4H8 { float4 f4; __half2 h2[4]; };

// Per plane: m[n][c][0:32] = tanh(x @ inW + inb), m[n][c][32:36] = x (same across c)
__global__ void k_init(const float* __restrict__ x, const float* __restrict__ W,
                       const float* __restrict__ b, float* __restrict__ m) {
    unsigned t = blockIdx.x * 256 + threadIdx.x;
    if (t >= N_NODES * HI) return;
    unsigned idx = t % HI;
    unsigned n   = t / HI;
    float x0 = x[n * 4 + 0], x1 = x[n * 4 + 1];
    float x2 = x[n * 4 + 2], x3 = x[n * 4 + 3];
    float val;
    if (idx < 32) {
        float a = b[idx];
        a += x0 * W[idx] + x1 * W[32 + idx] + x2 * W[64 + idx] + x3 * W[96 + idx];
        val = fast_tanh(a);
    } else {
        val = (idx == 32) ? x0 : (idx == 33) ? x1 : (idx == 34) ? x2 : x3;
    }
    float* dst = m + (size_t)n * (NCLS * HI) + idx;
    dst[0] = val; dst[HI] = val; dst[2 * HI] = val; dst[3 * HI] = val;
}

// ---------------- CSR build (per plane, once) ----------------
__global__ void k_hist(const int* __restrict__ rowI, const int* __restrict__ colI,
                       int* __restrict__ inCnt, int* __restrict__ outCnt) {
    unsigned e = blockIdx.x * 256 + threadIdx.x;
    if (e >= N_EDGES) return;
    atomicAdd(&inCnt[colI[e]], 1);
    atomicAdd(&outCnt[rowI[e]], 1);
}

// Exclusive scan. block 0: raw in -> inOffRaw; block 1: padded-8 in -> pinOff;
// block 2: padded-8 out -> poutOff.
__global__ void k_scan(const int* __restrict__ inCnt, const int* __restrict__ outCnt,
                       int* __restrict__ inOffRaw, int* __restrict__ pinOff,
                       int* __restrict__ poutOff) {
    const int* cnt = (blockIdx.x == 2) ? outCnt : inCnt;
    int* off = (blockIdx.x == 0) ? inOffRaw : (blockIdx.x == 1) ? pinOff : poutOff;
    bool pad = blockIdx.x != 0;
    __shared__ int sh[16];
    __shared__ int carry;
    int tid = threadIdx.x;            // 1024
    int lane = tid & 63, wid = tid >> 6;
    if (tid == 0) carry = 0;
    __syncthreads();
    for (int base = 0; base < N_NODES; base += 1024) {
        int i = base + tid;
        int v = (i < N_NODES) ? cnt[i] : 0;
        if (pad) v = (v + 7) & ~7;
        int val = v;
#pragma unroll
        for (int d = 1; d < 64; d <<= 1) {
            int t = __shfl_up(val, d, 64);
            if (lane >= d) val += t;
        }
        if (lane == 63) sh[wid] = val;
        __syncthreads();
        if (tid < 16) {
            int s = sh[tid];
#pragma unroll
            for (int d = 1; d < 16; d <<= 1) {
                int t = __shfl_up(s, d, 16);
                if (tid >= d) s += t;
            }
            sh[tid] = s;
        }
        __syncthreads();
        int waveOff = (wid == 0) ? 0 : sh[wid - 1];
        int incl = val + waveOff + carry;
        if (i < N_NODES) off[i] = incl - v;
        __syncthreads();
        if (tid == 1023) carry = incl;
        __syncthreads();
    }
    if (tid == 0) off[N_NODES] = carry;
}

// Dense in-CSR entry for k_edge: inL2[dense]=(row|col<<16, piP), poPA[dense]=poP,
// eArr[dense]=e. Padded gather arrays: inPrt[piP]=row, outPrt[poP]=col
// (pad slots stay 0 from the per-plane memset).
__global__ void k_fill(const int* __restrict__ rowI, const int* __restrict__ colI,
                       const int* __restrict__ inOffRaw, const int* __restrict__ pinOff,
                       const int* __restrict__ poutOff,
                       int* __restrict__ inCur, int* __restrict__ outCur,
                       int2* __restrict__ inL2, int* __restrict__ poPA,
                       int* __restrict__ eArr,
                       unsigned short* __restrict__ inPrt,
                       unsigned short* __restrict__ outPrt) {
    unsigned e = blockIdx.x * 256 + threadIdx.x;
    if (e >= N_EDGES) return;
    int r = rowI[e], cn = colI[e];
    int liIn  = atomicAdd(&inCur[cn], 1);
    int liOut = atomicAdd(&outCur[r], 1);
    int dense = inOffRaw[cn] + liIn;
    int piP   = pinOff[cn] + liIn;
    int poP   = poutOff[r] + liOut;
    inL2[dense] = make_int2(r | (cn << 16), piP);
    poPA[dense] = poP;
    eArr[dense] = (int)e;
    inPrt[piP]  = (unsigned short)r;
    outPrt[poP] = (unsigned short)cn;
}

// ---------------- per-iteration kernels ----------------

// Column-resident GEMM: thread owns one output column (Wcol[36] in VGPRs),
// loops RPB row-pairs with wave-broadcast m loads. NSUB=4: u|v|p|q; NSUB=2: u|v.
template <int NSUB, int RPB>
__global__ void k_gemm(const float* __restrict__ m,
                       const float* __restrict__ W0, const float* __restrict__ W1,
                       const float* __restrict__ W2, const float* __restrict__ W3,
                       __half* __restrict__ o0, __half* __restrict__ o1,
                       __half* __restrict__ o2, __half* __restrict__ o3) {
    constexpr int COLS = NSUB * 32;
    constexpr int NSTR = 256 / COLS;
    unsigned tid = threadIdx.x;
    unsigned o = tid % COLS, stream = tid / COLS;
    unsigned sub = o >> 5, oo = o & 31;
    const float* W = (sub == 0) ? W0 : (sub == 1) ? W1 : (sub == 2) ? W2 : W3;
    __half* dst    = (sub == 0) ? o0 : (sub == 1) ? o1 : (sub == 2) ? o2 : o3;
    float wcol[36];
#pragma unroll
    for (int k = 0; k < 36; ++k) wcol[k] = W[k * 32 + oo];
    unsigned rpBase = blockIdx.x * RPB;
    for (unsigned i = stream; i < RPB; i += NSTR) {
        unsigned r0 = (rpBase + i) * 2;
        const float4* m4 = reinterpret_cast<const float4*>(m + (size_t)r0 * HI);
        float4 v0[9], v1[9];
#pragma unroll
        for (int t = 0; t < 9; ++t) { v0[t] = m4[t]; v1[t] = m4[t + 9]; }
        const float* mr0 = (const float*)v0;
        const float* mr1 = (const float*)v1;
        float a0 = 0.f, a1 = 0.f;
#pragma unroll
        for (int k = 0; k < 36; ++k) { a0 += mr0[k] * wcol[k]; a1 += mr1[k] * wcol[k]; }
        dst[(size_t)r0 * 32 + oo]       = __float2half_rn(a0);
        dst[(size_t)(r0 + 1) * 32 + oo] = __float2half_rn(a1);
    }
}

// Edges in in-CSR order (grouped by col -> u side L1-resident).
// Per (idx,c): s = tanh(sum_o tanh(u[col]+v[row]+b1)*w2 + b2); softmax over c (4 lanes).
template <bool FINAL>
__global__ void k_edge(const int2* __restrict__ inL2, const int* __restrict__ poPA,
                       const int* __restrict__ eArr,
                       const __half* __restrict__ u, const __half* __restrict__ v,
                       const float* __restrict__ b1, const float* __restrict__ w2,
                       const float* __restrict__ b2,
                       float* __restrict__ eaIn, float* __restrict__ eaOut,
                       float* __restrict__ dst) {
    unsigned g   = blockIdx.x * 256 + threadIdx.x;   // exact grid: E*4
    unsigned c   = g & 3;
    unsigned idx = g >> 2;
    int2 ent = inL2[idx];
    unsigned rc  = (unsigned)ent.x;
    unsigned row = rc & 0xFFFFu, col = rc >> 16;
    const float4* u4 = reinterpret_cast<const float4*>(u + (col * 4 + c) * 32);
    const float4* v4 = reinterpret_cast<const float4*>(v + (row * 4 + c) * 32);
    float t2 = b2[0];
#pragma unroll
    for (int i = 0; i < 4; ++i) {          // 4 x (16B = 8 halves)
        F4H8 U, V; U.f4 = u4[i]; V.f4 = v4[i];
#pragma unroll
        for (int jj = 0; jj < 4; ++jj) {
            float2 uf = __half22float2(U.h2[jj]);
            float2 vf = __half22float2(V.h2[jj]);
            int o = i * 8 + jj * 2;
            t2 += fast_tanh(uf.x + vf.x + b1[o])     * w2[o];
            t2 += fast_tanh(uf.y + vf.y + b1[o + 1]) * w2[o + 1];
        }
    }
    float s  = fast_tanh(t2);
    float m1 = fmaxf(s, __shfl_xor(s, 1, 4));
    float mx = fmaxf(m1, __shfl_xor(m1, 2, 4));
    float ex = __expf(s - mx);
    float sm = ex + __shfl_xor(ex, 1, 4);
    sm = sm + __shfl_xor(sm, 2, 4);
    float val = ex / sm;
    if (FINAL) {
        dst[(unsigned)eArr[idx] * 4 + c] = val;
    } else {
        eaIn[(unsigned)ent.y * 4 + c] = val;
        eaOut[(unsigned)poPA[idx] * 4 + c] = val;
    }
}

// Fused node net, padded batch-8 gathers (no conditionals in the hot loop).
// h = m@C + nb1 + sum_in eaIn*p[prt] + sum_out eaOut*q[prt];
// H = tanh(tanh(h) @ nW2 + nb2) -> m[row][0:32] in place. 8 rows x 32 lanes.
__global__ void k_node(float* __restrict__ m,
                       const __half* __restrict__ p, const __half* __restrict__ q,
                       const float* __restrict__ eaIn, const float* __restrict__ eaOut,
                       const int* __restrict__ pinOff, const int* __restrict__ poutOff,
                       const unsigned short* __restrict__ inPrt,
                       const unsigned short* __restrict__ outPrt,
                       const float* __restrict__ WC, const float* __restrict__ nb1,
                       const float* __restrict__ nW2, const float* __restrict__ nb2) {
    __shared__ float sC[36 * 32];
    __shared__ float sW2[32 * 32];
    __shared__ float tb[8 * 33];
    unsigned tid = threadIdx.x;
    for (unsigned i = tid; i < 36 * 32; i += 256) sC[i] = WC[i];
    for (unsigned i = tid; i < 32 * 32; i += 256) sW2[i] = nW2[i];
    unsigned rl = tid >> 5, k = tid & 31;
    unsigned row = blockIdx.x * 8 + rl;   // flat (n*4 + c)
    unsigned n = row >> 2, c = row & 3;
    const float4* m4 = reinterpret_cast<const float4*>(m + (size_t)row * HI);
    float mr[36];
#pragma unroll
    for (int i = 0; i < 9; ++i) {
        float4 v = m4[i];
        mr[4 * i] = v.x; mr[4 * i + 1] = v.y; mr[4 * i + 2] = v.z; mr[4 * i + 3] = v.w;
    }
    __syncthreads();
    float h = nb1[k];
#pragma unroll
    for (int kk = 0; kk < 36; ++kk) h += mr[kk] * sC[kk * 32 + k];

    unsigned gOff = c * 32 + k;
    {   // in-gather (padded length, multiple of 8; pad slots have prt=0, ea=0)
        int b1i = pinOff[n + 1];
        for (int b = pinOff[n]; b < b1i; b += 8) {
            unsigned prt[8]; float av[8];
#pragma unroll
            for (int i = 0; i < 8; ++i) {
                prt[i] = inPrt[b + i];
                av[i]  = eaIn[(unsigned)(b + i) * 4 + c];
            }
#pragma unroll
            for (int i = 0; i < 8; ++i)
                h += av[i] * __half2float(p[prt[i] * 128u + gOff]);
        }
    }
    {   // out-gather
        int b1o = poutOff[n + 1];
        for (int b = poutOff[n]; b < b1o; b += 8) {
            unsigned prt[8]; float av[8];
#pragma unroll
            for (int i = 0; i < 8; ++i) {
                prt[i] = outPrt[b + i];
                av[i]  = eaOut[(unsigned)(b + i) * 4 + c];
            }
#pragma unroll
            for (int i = 0; i < 8; ++i)
                h += av[i] * __half2float(q[prt[i] * 128u + gOff]);
        }
    }
    float t = fast_tanh(h);
    tb[rl * 33 + k] = t;
    __syncthreads();
    float hh = nb2[k];
#pragma unroll
    for (int kk = 0; kk < 32; ++kk) hh += tb[rl * 33 + kk] * sW2[kk * 32 + k];
    m[(size_t)row * HI + k] = fast_tanh(hh);
}

extern "C" void kernel_launch(void* const* d_in, const int* in_sizes, int n_in,
                              void* d_out, int out_size, void* d_ws, size_t ws_size,
                              hipStream_t stream) {
    const float* x   = (const float*)d_in[0];
    const int*   ei  = (const int*)d_in[1];
    const float* inW = (const float*)d_in[2];
    const float* inb = (const float*)d_in[3];
    const float* eW1 = (const float*)d_in[4];
    const float* eb1 = (const float*)d_in[5];
    const float* eW2 = (const float*)d_in[6];
    const float* eb2 = (const float*)d_in[7];
    const float* nW1 = (const float*)d_in[8];
    const float* nb1 = (const float*)d_in[9];
    const float* nW2 = (const float*)d_in[10];
    const float* nb2 = (const float*)d_in[11];
    float* out = (float*)d_out;

    // Workspace (~112 MB): m 28.8 | u,v,p,q fp16 51.2 | eaIn/eaOut 21.5 |
    // inL2 3.2 | poPA 1.6 | eArr 1.6 | prt u16 2.7 | offsets/counts ~1.0
    float*  m     = (float*)d_ws;
    __half* u     = (__half*)(m + (size_t)ROWS_P * HI);
    __half* v     = u + (size_t)ROWS_P * 32;
    __half* p     = v + (size_t)ROWS_P * 32;
    __half* q     = p + (size_t)ROWS_P * 32;
    float*  eaIn  = (float*)(q + (size_t)ROWS_P * 32);
    float*  eaOut = eaIn + (size_t)PADCAP * 4;
    int2*   inL2  = (int2*)(eaOut + (size_t)PADCAP * 4);
    int*    poPA  = (int*)(inL2 + N_EDGES);
    int*    eArr  = poPA + N_EDGES;
    unsigned short* inPrt  = (unsigned short*)(eArr + N_EDGES);
    unsigned short* outPrt = inPrt + PADCAP;
    int*    inOffRaw = (int*)(outPrt + PADCAP);
    int*    pinOff   = inOffRaw + (N_NODES + 1);
    int*    poutOff  = pinOff + (N_NODES + 1);
    int*    inCur    = poutOff + (N_NODES + 1);
    int*    outCur   = inCur + N_NODES;

    const int gridE = (N_EDGES + 255) / 256;

    for (int j = 0; j < 3; ++j) {
        const int*   rowI = ei + (size_t)j * 2 * N_EDGES;
        const int*   colI = rowI + N_EDGES;
        const float* eW1j = eW1 + j * 72 * 32;
        const float* eb1j = eb1 + j * 32;
        const float* eW2j = eW2 + j * 32;
        const float* eb2j = eb2 + j;
        const float* nW1j = nW1 + j * 108 * 32;
        const float* nb1j = nb1 + j * 32;
        const float* nW2j = nW2 + j * 1024;
        const float* nb2j = nb2 + j * 32;

        // CSR build (padded)
        hipMemsetAsync(inCur, 0, 2 * N_NODES * sizeof(int), stream);
        k_hist<<<gridE, 256, 0, stream>>>(rowI, colI, inCur, outCur);
        k_scan<<<3, 1024, 0, stream>>>(inCur, outCur, inOffRaw, pinOff, poutOff);
        hipMemsetAsync(inCur, 0, 2 * N_NODES * sizeof(int), stream);
        hipMemsetAsync(inPrt, 0, 2 * (size_t)PADCAP * sizeof(unsigned short), stream);
        hipMemsetAsync(eaIn, 0, 2 * (size_t)PADCAP * 4 * sizeof(float), stream);
        k_fill<<<gridE, 256, 0, stream>>>(rowI, colI, inOffRaw, pinOff, poutOff,
                                          inCur, outCur, inL2, poPA, eArr, inPrt, outPrt);

        k_init<<<(N_NODES * HI + 255) / 256, 256, 0, stream>>>(
            x + (size_t)j * N_NODES * 4, inW + j * 128, inb + j * 32, m);

        for (int it = 0; it < 3; ++it) {
            k_gemm<4, 16><<<ROWS_P / 2 / 16, 256, 0, stream>>>(
                m, eW1j, eW1j + 36 * 32, nW1j, nW1j + 36 * 32, u, v, p, q);
            k_edge<false><<<N_EDGES * 4 / 256, 256, 0, stream>>>(
                inL2, poPA, eArr, u, v, eb1j, eW2j, eb2j, eaIn, eaOut, nullptr);
            k_node<<<ROWS_P / 8, 256, 0, stream>>>(m, p, q, eaIn, eaOut,
                                                   pinOff, poutOff, inPrt, outPrt,
                                                   nW1j + 72 * 32, nb1j, nW2j, nb2j);
        }
        k_gemm<2, 16><<<ROWS_P / 2 / 16, 256, 0, stream>>>(
            m, eW1j, eW1j + 36 * 32, eW1j, eW1j, u, v, u, v);
        k_edge<true><<<N_EDGES * 4 / 256, 256, 0, stream>>>(
            inL2, poPA, eArr, u, v, eb1j, eW2j, eb2j, nullptr, nullptr,
            out + (size_t)j * N_EDGES * 4);
    }
}